// Round 1
// 328.196 us; speedup vs baseline: 1.1862x; 1.1862x over previous
//
#include <hip/hip_runtime.h>

// HyperConnections fused kernel (fp32 I/O, fp32 math) — v2: multi-token blocks.
//
// out[t,:] = residual[t,:] * (SB + E*tanh(dotB*inv_rms)*beta_scale)
//          + x[t,:]        * (SA + E*sum_{i=1..E} tanh(dotA_i*inv_rms)*alpha_scale)
// dotA_i = sum_d x[d]*w[d]*fnA[d][i] (i=1..E; column 0 is provably unused),
// dotB   = sum_d x[d]*w[d]*fnB[d],  inv_rms = rsqrt(mean(x^2)+eps).
//
// v2 changes vs v1 (which was latency-bound: VALUBusy 9%, HBM 18%):
//  - TPB=8 tokens per block: weights (w, fnB, fnA) loaded ONCE per block and
//    pre-combined into registers (wa[d][i]=w*fnA_i, wb[d]=w*fnB). Kills the
//    per-token 56KB weight re-fetch incl. the uncoalesced 160B-stride fnA reads.
//  - software pipeline: x/resid for token t+1 issued before token t's reduction.
//  - raw s_barrier with lgkmcnt(0) only (no vmcnt drain) so prefetch loads stay
//    in flight across the barrier; ONE barrier/token via double-buffered red[].
//  - 2nd barrier + single-lane libm tanhf removed: every thread computes the 5
//    tanhs with hw exp2/rcp: tanh(z) = 1 - 2*rcp(exp2(2*log2e*z)+1).
//    Exact 0 at z=0 and saturates to +-1, so reference-exactness is preserved.

#define D_MODEL 2048
#define E_RATE 4
#define HC_EPS 1e-5f
#define NT 256
#define EPT 8   // elements per thread: 2048/256
#define TPB 8   // tokens per block

__device__ __forceinline__ float fast_tanh(float z) {
    // tanh(z) = 1 - 2/(exp2(z*2*log2(e)) + 1)
    // z=0 -> exp2=1 -> 1-2*rcp(2)=0 exactly; z->+inf -> 1; z->-inf -> -1.
    const float e = __builtin_amdgcn_exp2f(z * 2.8853900817779268f);
    return fmaf(-2.0f, __builtin_amdgcn_rcpf(e + 1.0f), 1.0f);
}

extern "C" __global__ void __launch_bounds__(NT, 4)
hc_kernel(const float* __restrict__ x,
          const float* __restrict__ resid,
          const float* __restrict__ w,
          const float* __restrict__ sA,     // [E, E+1] = [4,5]
          const float* __restrict__ sB,     // [E]
          const float* __restrict__ fnA,    // [D, E+1]
          const float* __restrict__ aScale, // [1]
          const float* __restrict__ fnB,    // [D]
          const float* __restrict__ bScale, // [1]
          float* __restrict__ out,
          const int n_tokens)
{
    const int tid  = threadIdx.x;
    const int tok0 = blockIdx.x * TPB;
    const int ntok = min(TPB, n_tokens - tok0);
    const int wave = tid >> 6, lane = tid & 63;

    // ---- persistent per-thread weights (loaded once per block) ----
    float4 w0 = ((const float4*)w)[2 * tid];
    float4 w1 = ((const float4*)w)[2 * tid + 1];
    float4 b0 = ((const float4*)fnB)[2 * tid];
    float4 b1 = ((const float4*)fnB)[2 * tid + 1];

    float wf[EPT]  = {w0.x, w0.y, w0.z, w0.w, w1.x, w1.y, w1.z, w1.w};
    float fbf[EPT] = {b0.x, b0.y, b0.z, b0.w, b1.x, b1.y, b1.z, b1.w};

    float wb[EPT];
#pragma unroll
    for (int d = 0; d < EPT; d++) wb[d] = wf[d] * fbf[d];

    // fnA rows d0..d0+7 = 40 consecutive fp32 at tid*40; keep cols 1..4 * w[d]
    float wa[EPT][E_RATE];
    const float4* fa4 = (const float4*)fnA;
#pragma unroll
    for (int j = 0; j < 10; j++) {
        float4 t4 = fa4[(size_t)tid * 10 + j];
        float fv[4] = {t4.x, t4.y, t4.z, t4.w};
#pragma unroll
        for (int q = 0; q < 4; q++) {
            const int e = j * 4 + q;   // flat in [0,40)
            const int d = e / 5;       // compile-time after unroll
            const int i = e % 5;
            if (i >= 1) wa[d][i - 1] = fv[q] * wf[d];
        }
    }

    // ---- uniform scalars (scalar loads, broadcast) ----
    const float SB = sB[0] + sB[1] + sB[2] + sB[3];
    float SA = 0.0f;
#pragma unroll
    for (int i = 1; i <= E_RATE; i++)
#pragma unroll
        for (int j = 0; j < E_RATE; j++) SA += sA[j * (E_RATE + 1) + i];
    const float asc = aScale[0];
    const float bsc = bScale[0];

    __shared__ float red[2][4][8];  // [parity][wave][6 used, padded to 8]

    const int F4 = D_MODEL / 4;  // 512 float4 per token row
    const float4* xr   = (const float4*)(x     + (size_t)tok0 * D_MODEL);
    const float4* rr   = (const float4*)(resid + (size_t)tok0 * D_MODEL);
    float4*       orow = (float4*)(out + (size_t)tok0 * D_MODEL);

    // prefetch token 0
    float4 xn0 = xr[2 * tid], xn1 = xr[2 * tid + 1];
    float4 rn0 = rr[2 * tid], rn1 = rr[2 * tid + 1];

    for (int t = 0; t < ntok; ++t) {
        const float4 x0 = xn0, x1 = xn1, r0 = rn0, r1 = rn1;
        if (t + 1 < ntok) {  // issue next token's loads before the reduction
            const int nb = (t + 1) * F4 + 2 * tid;
            xn0 = xr[nb]; xn1 = xr[nb + 1];
            rn0 = rr[nb]; rn1 = rr[nb + 1];
        }

        const float xf[EPT] = {x0.x, x0.y, x0.z, x0.w, x1.x, x1.y, x1.z, x1.w};

        // ---- 6 partials: da[0..3], db(4), ssq(5) — 48 fmacs ----
        float vals[6] = {0.f, 0.f, 0.f, 0.f, 0.f, 0.f};
#pragma unroll
        for (int d = 0; d < EPT; d++) {
            vals[5] = fmaf(xf[d], xf[d], vals[5]);
            vals[4] = fmaf(xf[d], wb[d], vals[4]);
            vals[0] = fmaf(xf[d], wa[d][0], vals[0]);
            vals[1] = fmaf(xf[d], wa[d][1], vals[1]);
            vals[2] = fmaf(xf[d], wa[d][2], vals[2]);
            vals[3] = fmaf(xf[d], wa[d][3], vals[3]);
        }

        // ---- wave-64 butterfly ----
#pragma unroll
        for (int j = 0; j < 6; j++) {
            float v = vals[j];
#pragma unroll
            for (int off = 32; off > 0; off >>= 1) v += __shfl_xor(v, off, 64);
            vals[j] = v;
        }

        // ---- cross-wave: one raw barrier, double-buffered, no vmcnt drain ----
        const int p = t & 1;
        if (lane == 0) {
#pragma unroll
            for (int j = 0; j < 6; j++) red[p][wave][j] = vals[j];
        }
        asm volatile("s_waitcnt lgkmcnt(0)" ::: "memory");
        __builtin_amdgcn_s_barrier();
        asm volatile("" ::: "memory");

        float tot[6];
#pragma unroll
        for (int j = 0; j < 6; j++)
            tot[j] = (red[p][0][j] + red[p][1][j]) + (red[p][2][j] + red[p][3][j]);

        const float inv  = rsqrtf(tot[5] * (1.0f / D_MODEL) + HC_EPS);
        const float dynb = fast_tanh(tot[4] * inv) * bsc;
        float dyna = 0.0f;
#pragma unroll
        for (int i = 0; i < E_RATE; i++) dyna += fast_tanh(tot[i] * inv);

        const float cR = SB + (float)E_RATE * dynb;
        const float cX = SA + (float)E_RATE * (dyna * asc);

        // ---- epilogue ----
        float4 o0, o1;
        o0.x = fmaf(r0.x, cR, x0.x * cX);
        o0.y = fmaf(r0.y, cR, x0.y * cX);
        o0.z = fmaf(r0.z, cR, x0.z * cX);
        o0.w = fmaf(r0.w, cR, x0.w * cX);
        o1.x = fmaf(r1.x, cR, x1.x * cX);
        o1.y = fmaf(r1.y, cR, x1.y * cX);
        o1.z = fmaf(r1.z, cR, x1.z * cX);
        o1.w = fmaf(r1.w, cR, x1.w * cX);

        const int ob = t * F4 + 2 * tid;
        orow[ob]     = o0;
        orow[ob + 1] = o1;
    }
}

extern "C" void kernel_launch(void* const* d_in, const int* in_sizes, int n_in,
                              void* d_out, int out_size, void* d_ws, size_t ws_size,
                              hipStream_t stream) {
    const float* x      = (const float*)d_in[0];
    const float* resid  = (const float*)d_in[1];
    const float* w      = (const float*)d_in[2];
    const float* sA     = (const float*)d_in[3];
    const float* sB     = (const float*)d_in[4];
    const float* fnA    = (const float*)d_in[5];
    const float* aScale = (const float*)d_in[6];
    const float* fnB    = (const float*)d_in[7];
    const float* bScale = (const float*)d_in[8];
    float* out          = (float*)d_out;

    const int n_tokens = in_sizes[0] / D_MODEL;  // B*T = 16384
    const int grid = (n_tokens + TPB - 1) / TPB;

    hc_kernel<<<grid, NT, 0, stream>>>(x, resid, w, sA, sB, fnA, aScale,
                                       fnB, bScale, out, n_tokens);
}